// Round 6
// baseline (683.093 us; speedup 1.0000x reference)
//
#include <hip/hip_runtime.h>
#include <math.h>

// Problem constants (match reference)
#define NROWS 65536          // B*S = 16*4096
#define CIN   768
#define QCOUNT 524288.0      // NROWS * DDIM
#define RPW   4              // rows per wave
#define NBLK  (NROWS / (4 * RPW))   // 4096 blocks of 4 waves

// One wave processes RPW rows, A/B software pipeline.
// Lane mapping: dg = lane&7 (quantizer dim), lev = lane>>3 (codebook level).
// Wc (24KB) in XOR-swizzled LDS, read per row (conflict-free b128).
// We and be read from GLOBAL, coalesced (L2-hot) — proven fine in R2/R5.
// Occupancy plan (R5 post-mortem): VGPR<=128 via launch_bounds(256,4) and
// no beR register block -> 4 waves/SIMD = 16 waves/CU; LDS 24.6KB -> 4
// blocks/CU not binding. Spill tripwire: FETCH_SIZE must stay ~107MB.

// Distributing butterfly: reduce 8 per-lane f64 partials across 64 lanes,
// delivering zc[d] to lanes with (lane&7)==d. Fixed order, static selects.
#define REDUCE_TO_MINE(da, out)                                            \
    {                                                                      \
        double k0 = b0 ? da[1] : da[0], s0 = b0 ? da[0] : da[1];           \
        double k1 = b0 ? da[3] : da[2], s1 = b0 ? da[2] : da[3];           \
        double k2 = b0 ? da[5] : da[4], s2 = b0 ? da[4] : da[5];           \
        double k3 = b0 ? da[7] : da[6], s3 = b0 ? da[6] : da[7];           \
        k0 += __shfl_xor(s0, 1); k1 += __shfl_xor(s1, 1);                  \
        k2 += __shfl_xor(s2, 1); k3 += __shfl_xor(s3, 1);                  \
        double m0 = b1 ? k1 : k0, t0 = b1 ? k0 : k1;                       \
        double m1 = b1 ? k3 : k2, t1 = b1 ? k2 : k3;                       \
        m0 += __shfl_xor(t0, 2); m1 += __shfl_xor(t1, 2);                  \
        double r = b2 ? m1 : m0, tq = b2 ? m0 : m1;                        \
        r += __shfl_xor(tq, 4);                                            \
        r += __shfl_xor(r, 8);                                             \
        r += __shfl_xor(r, 16);                                            \
        r += __shfl_xor(r, 32);                                            \
        out = r;                                                           \
    }

// Load one row's z (3 coalesced float4) + u (coalesced permuted 256B)
#define LOADZ(B, row)                                                      \
    B##0 = z4[(size_t)(row) * 192 + lane];                                 \
    B##1 = z4[(size_t)(row) * 192 + lane + 64];                           \
    B##2 = z4[(size_t)(row) * 192 + lane + 128];                          \
    B##u = u[(size_t)(row) * 64 + dg * 8 + lev];

// compress: zc = z @ Wc (+bc). f32 FMA within 4-chunk, f64 chunk accum —
// EXACT same arithmetic order as the verified absmax-0.0 kernel; wA/wB
// sourced from swizzled LDS (same values).
#define COMPRESS(B, ZCOUT)                                                 \
    {                                                                      \
        double da[8];                                                      \
        _Pragma("unroll") for (int d = 0; d < 8; ++d) da[d] = 0.0;         \
        _Pragma("unroll") for (int j = 0; j < 3; ++j) {                    \
            const float4 zv = (j == 0) ? B##0 : (j == 1) ? B##1 : B##2;    \
            const int fi = lane + 64 * j;                                  \
            const int sw = fi & 7;                                         \
            float f[8];                                                    \
            _Pragma("unroll") for (int d = 0; d < 8; ++d) f[d] = 0.f;      \
            _Pragma("unroll") for (int k = 0; k < 4; ++k) {                \
                const float a = (k==0)?zv.x:(k==1)?zv.y:(k==2)?zv.z:zv.w;  \
                const int a0 = 8 * fi + 2 * k;                             \
                const float4 wA = lds_w[a0 ^ sw];                          \
                const float4 wB = lds_w[(a0 + 1) ^ sw];                    \
                f[0]=fmaf(a,wA.x,f[0]); f[1]=fmaf(a,wA.y,f[1]);            \
                f[2]=fmaf(a,wA.z,f[2]); f[3]=fmaf(a,wA.w,f[3]);            \
                f[4]=fmaf(a,wB.x,f[4]); f[5]=fmaf(a,wB.y,f[5]);            \
                f[6]=fmaf(a,wB.z,f[6]); f[7]=fmaf(a,wB.w,f[7]);            \
            }                                                              \
            _Pragma("unroll") for (int d = 0; d < 8; ++d)                  \
                da[d] += (double)f[d];                                     \
        }                                                                  \
        REDUCE_TO_MINE(da, ZCOUT)                                         \
        ZCOUT += bc_mine;                                                  \
    }

// gumbel + argmax + qerr-accumulate + expand(We,be from global) + store
#define FINISH(row, ZC, UVF)                                               \
    {                                                                      \
        const double uv = (double)(UVF) + 1e-10;                           \
        const double g  = -log(-log(uv));                                  \
        double n  = g - fabs(ZC - (double)cb_mine);   /* TAU = 1 */        \
        int    li = lev;                                                   \
        float  ci = cb_mine;                                               \
        _Pragma("unroll") for (int s = 8; s <= 32; s <<= 1) {              \
            const double on = __shfl_xor(n, s);                            \
            const int    ol = __shfl_xor(li, s);                           \
            const float  oc = __shfl_xor(ci, s);                           \
            const bool   t  = (on > n) || (on == n && ol < li);            \
            n = t ? on : n; li = t ? ol : li; ci = t ? oc : ci;            \
        }                                                                  \
        const double e = ZC - (double)ci;                                  \
        qa += e * e;                                                       \
        float code[8];                                                     \
        _Pragma("unroll") for (int d = 0; d < 8; ++d)                      \
            code[d] = __shfl(ci, (lane & 56) | d);                         \
        _Pragma("unroll") for (int j = 0; j < 3; ++j) {                    \
            const int fi = lane + 64 * j;                                  \
            float4 o = be4[fi];                                            \
            _Pragma("unroll") for (int d = 0; d < 8; ++d) {                \
                const float4 wv = We4[d * 192 + fi];                       \
                o.x = fmaf(code[d], wv.x, o.x);                            \
                o.y = fmaf(code[d], wv.y, o.y);                            \
                o.z = fmaf(code[d], wv.z, o.z);                            \
                o.w = fmaf(code[d], wv.w, o.w);                            \
            }                                                              \
            zq4[(size_t)(row) * 192 + fi] = o;                             \
        }                                                                  \
    }

template <int USE_BPART>
__global__ __launch_bounds__(256, 4) void fsq_main(
    const float* __restrict__ z, const float* __restrict__ u,
    const float* __restrict__ Wc, const float* __restrict__ bc,
    const float* __restrict__ We, const float* __restrict__ be,
    const float* __restrict__ cb, float* __restrict__ zq,
    double* __restrict__ bpart)
{
    __shared__ float4 lds_w[1536];   // Wc, XOR-swizzled
    __shared__ double wsum[4];

    const int lane = threadIdx.x & 63;
    const int wid  = threadIdx.x >> 6;
    const int dg   = lane & 7;
    const int lev  = lane >> 3;

    // ---- stage Wc into LDS, XOR-swizzled (idx ^ ((idx>>3)&7), involution) ----
    {
        const float4* __restrict__ Wc4 = (const float4*)Wc;
        for (int t = threadIdx.x; t < 1536; t += 256)
            lds_w[t ^ ((t >> 3) & 7)] = Wc4[t];
    }

    const float  cb_mine = cb[dg * 8 + lev];
    const double bc_mine = (double)bc[dg];
    const int b0 = lane & 1, b1 = (lane >> 1) & 1, b2 = (lane >> 2) & 1;

    const float4* __restrict__ z4  = (const float4*)z;
    const float4* __restrict__ We4 = (const float4*)We;
    const float4* __restrict__ be4 = (const float4*)be;
    float4* __restrict__ zq4 = (float4*)zq;

    const int wbase = (blockIdx.x * 4 + wid) * RPW;
    double qa = 0.0;

    __syncthreads();   // Wc image ready

    // ---- row loop: 2 rows per trip, A/B software pipeline ----
    float4 zA0, zA1, zA2, zB0, zB1, zB2;
    float  zAu, zBu;
    double zcA, zcB;
    LOADZ(zA, wbase)
#pragma unroll 1
    for (int itp = 0; itp < RPW / 2; ++itp) {
        const int r0 = wbase + 2 * itp;
        LOADZ(zB, r0 + 1)                 // issue early: hides under COMPRESS+FINISH(A)
        COMPRESS(zA, zcA)
        const float uvA = zAu;
        FINISH(r0, zcA, uvA)
        COMPRESS(zB, zcB)
        const float uvB = zBu;
        if (itp != RPW / 2 - 1) { LOADZ(zA, r0 + 2) }  // prefetch next trip
        FINISH(r0 + 1, zcB, uvB)
    }

    // ---- quantization error: dg-reduce once per wave ----
    qa += __shfl_xor(qa, 1);
    qa += __shfl_xor(qa, 2);
    qa += __shfl_xor(qa, 4);
    if (USE_BPART) {
        if (lane == 0) wsum[wid] = qa;
        __syncthreads();
        if (threadIdx.x == 0)
            bpart[blockIdx.x] = (wsum[0] + wsum[1]) + (wsum[2] + wsum[3]);
    } else {
        if (lane == 0) atomicAdd(bpart, qa);
    }
}

// Deterministic fixed-order reduction of NBLK partials -> mean -> out.
__global__ __launch_bounds__(256) void fsq_tail_bpart(
    const double* __restrict__ bpart, float* __restrict__ out)
{
    __shared__ double s[256];
    const int t = threadIdx.x;
    double a = 0.0;
    for (int i = 0; i < NBLK / 256; ++i)          // fixed order
        a += bpart[t * (NBLK / 256) + i];
    s[t] = a;
    __syncthreads();
    for (int w = 128; w > 0; w >>= 1) {
        if (t < w) s[t] += s[t + w];
        __syncthreads();
    }
    if (t == 0) out[0] = (float)(s[0] * (1.0 / QCOUNT));
}

__global__ void fsq_tail_atomic(const double* __restrict__ qacc, float* __restrict__ out)
{
    out[0] = (float)(qacc[0] * (1.0 / QCOUNT));
}

extern "C" void kernel_launch(void* const* d_in, const int* in_sizes, int n_in,
                              void* d_out, int out_size, void* d_ws, size_t ws_size,
                              hipStream_t stream)
{
    const float* z  = (const float*)d_in[0];
    const float* u  = (const float*)d_in[1];
    const float* Wc = (const float*)d_in[2];
    const float* bc = (const float*)d_in[3];
    const float* We = (const float*)d_in[4];
    const float* be = (const float*)d_in[5];
    const float* cb = (const float*)d_in[6];
    // d_in[7] = codebook_mask: all levels == 8 -> mask all true, unused.

    float*  zq    = (float*)d_out;
    double* bpart = (double*)d_ws;

    if (ws_size >= (size_t)NBLK * sizeof(double)) {
        // no memset needed: every block overwrites its own slot
        fsq_main<1><<<dim3(NBLK), dim3(256), 0, stream>>>(z, u, Wc, bc, We, be, cb, zq, bpart);
        fsq_tail_bpart<<<dim3(1), dim3(256), 0, stream>>>(bpart, zq + (size_t)NROWS * CIN);
    } else {
        hipMemsetAsync(d_ws, 0, sizeof(double), stream);
        fsq_main<0><<<dim3(NBLK), dim3(256), 0, stream>>>(z, u, Wc, bc, We, be, cb, zq, bpart);
        fsq_tail_atomic<<<dim3(1), dim3(1), 0, stream>>>(bpart, zq + (size_t)NROWS * CIN);
    }
}

// Round 7
// 128.629 us; speedup vs baseline: 5.3106x; 5.3106x over previous
//
#include <hip/hip_runtime.h>
#include <math.h>

// Problem constants (match reference)
#define NROWS 65536          // B*S = 16*4096
#define CIN   768
#define QCOUNT 524288.0      // NROWS * DDIM
#define RPW   4              // rows per wave (pass 1 / mono)
#define NBLK  (NROWS / (4 * RPW))   // 4096 blocks of 4 waves
#define NBLK2 (NROWS / 8)           // 8192 blocks, expand: 2 rows/wave

// Two-pass structure (R6 post-mortem: mono kernel needs ~148 live VGPRs —
// caps spill, no-cap starves latency hiding). Waist = packed argmax codes,
// one uint32 per row (3b x 8 dims), 256KB total.
//   Pass 1 fsq_code:   z,u -> codes + qerr partials (f64 decision path)
//   Pass 2 fsq_expand: codes -> z_q (streaming, write-bound)
// Fallback to R5 mono kernel if ws too small for codes buffer.

// Distributing butterfly: reduce 8 per-lane f64 partials across 64 lanes,
// delivering zc[d] to lanes with (lane&7)==d. Fixed order, static selects.
#define REDUCE_TO_MINE(da, out)                                            \
    {                                                                      \
        double k0 = b0 ? da[1] : da[0], s0 = b0 ? da[0] : da[1];           \
        double k1 = b0 ? da[3] : da[2], s1 = b0 ? da[2] : da[3];           \
        double k2 = b0 ? da[5] : da[4], s2 = b0 ? da[4] : da[5];           \
        double k3 = b0 ? da[7] : da[6], s3 = b0 ? da[6] : da[7];           \
        k0 += __shfl_xor(s0, 1); k1 += __shfl_xor(s1, 1);                  \
        k2 += __shfl_xor(s2, 1); k3 += __shfl_xor(s3, 1);                  \
        double m0 = b1 ? k1 : k0, t0 = b1 ? k0 : k1;                       \
        double m1 = b1 ? k3 : k2, t1 = b1 ? k2 : k3;                       \
        m0 += __shfl_xor(t0, 2); m1 += __shfl_xor(t1, 2);                  \
        double r = b2 ? m1 : m0, tq = b2 ? m0 : m1;                        \
        r += __shfl_xor(tq, 4);                                            \
        r += __shfl_xor(r, 8);                                             \
        r += __shfl_xor(r, 16);                                            \
        r += __shfl_xor(r, 32);                                            \
        out = r;                                                           \
    }

// Load one row's z (3 coalesced float4) + u (coalesced permuted 256B)
#define LOADZ(B, row)                                                      \
    B##0 = z4[(size_t)(row) * 192 + lane];                                 \
    B##1 = z4[(size_t)(row) * 192 + lane + 64];                           \
    B##2 = z4[(size_t)(row) * 192 + lane + 128];                          \
    B##u = u[(size_t)(row) * 64 + dg * 8 + lev];

// compress: zc = z @ Wc (+bc). f32 FMA within 4-chunk, f64 chunk accum —
// EXACT same arithmetic order as the verified absmax-0.0 kernel; wA/wB
// sourced from XOR-swizzled LDS.
#define COMPRESS(B, ZCOUT)                                                 \
    {                                                                      \
        double da[8];                                                      \
        _Pragma("unroll") for (int d = 0; d < 8; ++d) da[d] = 0.0;         \
        _Pragma("unroll") for (int j = 0; j < 3; ++j) {                    \
            const float4 zv = (j == 0) ? B##0 : (j == 1) ? B##1 : B##2;    \
            const int fi = lane + 64 * j;                                  \
            const int sw = fi & 7;                                         \
            float f[8];                                                    \
            _Pragma("unroll") for (int d = 0; d < 8; ++d) f[d] = 0.f;      \
            _Pragma("unroll") for (int k = 0; k < 4; ++k) {                \
                const float a = (k==0)?zv.x:(k==1)?zv.y:(k==2)?zv.z:zv.w;  \
                const int a0 = 8 * fi + 2 * k;                             \
                const float4 wA = lds_w[a0 ^ sw];                          \
                const float4 wB = lds_w[(a0 + 1) ^ sw];                    \
                f[0]=fmaf(a,wA.x,f[0]); f[1]=fmaf(a,wA.y,f[1]);            \
                f[2]=fmaf(a,wA.z,f[2]); f[3]=fmaf(a,wA.w,f[3]);            \
                f[4]=fmaf(a,wB.x,f[4]); f[5]=fmaf(a,wB.y,f[5]);            \
                f[6]=fmaf(a,wB.z,f[6]); f[7]=fmaf(a,wB.w,f[7]);            \
            }                                                              \
            _Pragma("unroll") for (int d = 0; d < 8; ++d)                  \
                da[d] += (double)f[d];                                     \
        }                                                                  \
        REDUCE_TO_MINE(da, ZCOUT)                                         \
        ZCOUT += bc_mine;                                                  \
    }

// gumbel + argmax + qerr-accumulate + pack indices -> codes[row]
#define FIN_CODE(row, ZC, UVF)                                             \
    {                                                                      \
        const double uv = (double)(UVF) + 1e-10;                           \
        const double g  = -log(-log(uv));                                  \
        double n  = g - fabs(ZC - (double)cb_mine);   /* TAU = 1 */        \
        int    li = lev;                                                   \
        float  ci = cb_mine;                                               \
        _Pragma("unroll") for (int s = 8; s <= 32; s <<= 1) {              \
            const double on = __shfl_xor(n, s);                            \
            const int    ol = __shfl_xor(li, s);                           \
            const float  oc = __shfl_xor(ci, s);                           \
            const bool   t  = (on > n) || (on == n && ol < li);            \
            n = t ? on : n; li = t ? ol : li; ci = t ? oc : ci;            \
        }                                                                  \
        const double e = ZC - (double)ci;                                  \
        qa += e * e;                                                       \
        unsigned pk = (unsigned)li << (3 * dg);                            \
        pk += __shfl_xor(pk, 1);                                           \
        pk += __shfl_xor(pk, 2);                                           \
        pk += __shfl_xor(pk, 4);   /* full 24-bit pack in every lane */    \
        if (lane == 0) codes[row] = pk;                                    \
    }

// ---------------- Pass 1: compress + gumbel-argmax + qerr + codes ----------------
__global__ __launch_bounds__(256) void fsq_code(
    const float* __restrict__ z, const float* __restrict__ u,
    const float* __restrict__ Wc, const float* __restrict__ bc,
    const float* __restrict__ cb, unsigned* __restrict__ codes,
    double* __restrict__ bpart)
{
    __shared__ float4 lds_w[1536];   // Wc, XOR-swizzled
    __shared__ double wsum[4];

    const int lane = threadIdx.x & 63;
    const int wid  = threadIdx.x >> 6;
    const int dg   = lane & 7;
    const int lev  = lane >> 3;

    {
        const float4* __restrict__ Wc4 = (const float4*)Wc;
        for (int t = threadIdx.x; t < 1536; t += 256)
            lds_w[t ^ ((t >> 3) & 7)] = Wc4[t];
    }

    const float  cb_mine = cb[dg * 8 + lev];
    const double bc_mine = (double)bc[dg];
    const int b0 = lane & 1, b1 = (lane >> 1) & 1, b2 = (lane >> 2) & 1;

    const float4* __restrict__ z4 = (const float4*)z;

    const int wbase = (blockIdx.x * 4 + wid) * RPW;
    double qa = 0.0;

    __syncthreads();   // Wc image ready

    float4 zA0, zA1, zA2, zB0, zB1, zB2;
    float  zAu, zBu;
    double zcA, zcB;
    LOADZ(zA, wbase)
#pragma unroll 1
    for (int itp = 0; itp < RPW / 2; ++itp) {
        const int r0 = wbase + 2 * itp;
        LOADZ(zB, r0 + 1)
        COMPRESS(zA, zcA)
        const float uvA = zAu;
        FIN_CODE(r0, zcA, uvA)
        COMPRESS(zB, zcB)
        const float uvB = zBu;
        if (itp != RPW / 2 - 1) { LOADZ(zA, r0 + 2) }
        FIN_CODE(r0 + 1, zcB, uvB)
    }

    // qerr block partial (deterministic)
    qa += __shfl_xor(qa, 1);
    qa += __shfl_xor(qa, 2);
    qa += __shfl_xor(qa, 4);
    if (lane == 0) wsum[wid] = qa;
    __syncthreads();
    if (threadIdx.x == 0)
        bpart[blockIdx.x] = (wsum[0] + wsum[1]) + (wsum[2] + wsum[3]);
}

// ---------------- Pass 2: expand codes -> z_q (streaming) ----------------
__global__ __launch_bounds__(256) void fsq_expand(
    const unsigned* __restrict__ codes, const float* __restrict__ We,
    const float* __restrict__ be, const float* __restrict__ cb,
    float* __restrict__ zq)
{
    __shared__ float cbl[64];
    if (threadIdx.x < 64) cbl[threadIdx.x] = cb[threadIdx.x];
    __syncthreads();

    const int lane = threadIdx.x & 63;
    const int wid  = threadIdx.x >> 6;
    const int gw   = blockIdx.x * 4 + wid;
    const int row0 = gw * 2;
    const int row1 = row0 + 1;

    const unsigned c0 = codes[row0];   // wave-uniform broadcast load
    const unsigned c1 = codes[row1];

    float cd0[8], cd1[8];
#pragma unroll
    for (int d = 0; d < 8; ++d) {
        cd0[d] = cbl[d * 8 + ((c0 >> (3 * d)) & 7)];   // LDS broadcast read
        cd1[d] = cbl[d * 8 + ((c1 >> (3 * d)) & 7)];
    }

    const float4* __restrict__ We4 = (const float4*)We;
    const float4* __restrict__ be4 = (const float4*)be;
    float4* __restrict__ zq4 = (float4*)zq;
#pragma unroll
    for (int j = 0; j < 3; ++j) {
        const int fi = lane + 64 * j;
        const float4 bv = be4[fi];
        float4 o0 = bv, o1 = bv;
#pragma unroll
        for (int d = 0; d < 8; ++d) {
            const float4 wv = We4[d * 192 + fi];
            o0.x = fmaf(cd0[d], wv.x, o0.x);
            o0.y = fmaf(cd0[d], wv.y, o0.y);
            o0.z = fmaf(cd0[d], wv.z, o0.z);
            o0.w = fmaf(cd0[d], wv.w, o0.w);
            o1.x = fmaf(cd1[d], wv.x, o1.x);
            o1.y = fmaf(cd1[d], wv.y, o1.y);
            o1.z = fmaf(cd1[d], wv.z, o1.z);
            o1.w = fmaf(cd1[d], wv.w, o1.w);
        }
        zq4[(size_t)row0 * 192 + fi] = o0;
        zq4[(size_t)row1 * 192 + fi] = o1;
    }
}

// ---------------- mono fallback (R5 verified, 162us) ----------------
#define FINISH(row, ZC, UVF)                                               \
    {                                                                      \
        const double uv = (double)(UVF) + 1e-10;                           \
        const double g  = -log(-log(uv));                                  \
        double n  = g - fabs(ZC - (double)cb_mine);                        \
        int    li = lev;                                                   \
        float  ci = cb_mine;                                               \
        _Pragma("unroll") for (int s = 8; s <= 32; s <<= 1) {              \
            const double on = __shfl_xor(n, s);                            \
            const int    ol = __shfl_xor(li, s);                           \
            const float  oc = __shfl_xor(ci, s);                           \
            const bool   t  = (on > n) || (on == n && ol < li);            \
            n = t ? on : n; li = t ? ol : li; ci = t ? oc : ci;            \
        }                                                                  \
        const double e = ZC - (double)ci;                                  \
        qa += e * e;                                                       \
        float code[8];                                                     \
        _Pragma("unroll") for (int d = 0; d < 8; ++d)                      \
            code[d] = __shfl(ci, (lane & 56) | d);                         \
        _Pragma("unroll") for (int j = 0; j < 3; ++j) {                    \
            const int fi = lane + 64 * j;                                  \
            float4 o = be4[fi];                                            \
            _Pragma("unroll") for (int d = 0; d < 8; ++d) {                \
                const float4 wv = We4[d * 192 + fi];                       \
                o.x = fmaf(code[d], wv.x, o.x);                            \
                o.y = fmaf(code[d], wv.y, o.y);                            \
                o.z = fmaf(code[d], wv.z, o.z);                            \
                o.w = fmaf(code[d], wv.w, o.w);                            \
            }                                                              \
            zq4[(size_t)(row) * 192 + fi] = o;                             \
        }                                                                  \
    }

__global__ __launch_bounds__(256) void fsq_mono(
    const float* __restrict__ z, const float* __restrict__ u,
    const float* __restrict__ Wc, const float* __restrict__ bc,
    const float* __restrict__ We, const float* __restrict__ be,
    const float* __restrict__ cb, float* __restrict__ zq,
    double* __restrict__ bpart)
{
    __shared__ float4 lds_w[1536];
    __shared__ double wsum[4];

    const int lane = threadIdx.x & 63;
    const int wid  = threadIdx.x >> 6;
    const int dg   = lane & 7;
    const int lev  = lane >> 3;

    {
        const float4* __restrict__ Wc4 = (const float4*)Wc;
        for (int t = threadIdx.x; t < 1536; t += 256)
            lds_w[t ^ ((t >> 3) & 7)] = Wc4[t];
    }

    const float  cb_mine = cb[dg * 8 + lev];
    const double bc_mine = (double)bc[dg];
    const int b0 = lane & 1, b1 = (lane >> 1) & 1, b2 = (lane >> 2) & 1;

    const float4* __restrict__ z4  = (const float4*)z;
    const float4* __restrict__ We4 = (const float4*)We;
    const float4* __restrict__ be4 = (const float4*)be;
    float4* __restrict__ zq4 = (float4*)zq;

    const int wbase = (blockIdx.x * 4 + wid) * RPW;
    double qa = 0.0;

    __syncthreads();

    float4 zA0, zA1, zA2, zB0, zB1, zB2;
    float  zAu, zBu;
    double zcA, zcB;
    LOADZ(zA, wbase)
#pragma unroll 1
    for (int itp = 0; itp < RPW / 2; ++itp) {
        const int r0 = wbase + 2 * itp;
        LOADZ(zB, r0 + 1)
        COMPRESS(zA, zcA)
        const float uvA = zAu;
        FINISH(r0, zcA, uvA)
        COMPRESS(zB, zcB)
        const float uvB = zBu;
        if (itp != RPW / 2 - 1) { LOADZ(zA, r0 + 2) }
        FINISH(r0 + 1, zcB, uvB)
    }

    qa += __shfl_xor(qa, 1);
    qa += __shfl_xor(qa, 2);
    qa += __shfl_xor(qa, 4);
    if (lane == 0) wsum[wid] = qa;
    __syncthreads();
    if (threadIdx.x == 0)
        bpart[blockIdx.x] = (wsum[0] + wsum[1]) + (wsum[2] + wsum[3]);
}

// Deterministic fixed-order reduction of NBLK partials -> mean -> out.
__global__ __launch_bounds__(256) void fsq_tail_bpart(
    const double* __restrict__ bpart, float* __restrict__ out)
{
    __shared__ double s[256];
    const int t = threadIdx.x;
    double a = 0.0;
    for (int i = 0; i < NBLK / 256; ++i)          // fixed order
        a += bpart[t * (NBLK / 256) + i];
    s[t] = a;
    __syncthreads();
    for (int w = 128; w > 0; w >>= 1) {
        if (t < w) s[t] += s[t + w];
        __syncthreads();
    }
    if (t == 0) out[0] = (float)(s[0] * (1.0 / QCOUNT));
}

extern "C" void kernel_launch(void* const* d_in, const int* in_sizes, int n_in,
                              void* d_out, int out_size, void* d_ws, size_t ws_size,
                              hipStream_t stream)
{
    const float* z  = (const float*)d_in[0];
    const float* u  = (const float*)d_in[1];
    const float* Wc = (const float*)d_in[2];
    const float* bc = (const float*)d_in[3];
    const float* We = (const float*)d_in[4];
    const float* be = (const float*)d_in[5];
    const float* cb = (const float*)d_in[6];
    // d_in[7] = codebook_mask: all levels == 8 -> mask all true, unused.

    float*  zq    = (float*)d_out;
    double* bpart = (double*)d_ws;

    const size_t bpart_bytes = (size_t)NBLK * sizeof(double);       // 32 KB
    const size_t codes_bytes = (size_t)NROWS * sizeof(unsigned);    // 256 KB

    if (ws_size >= bpart_bytes + codes_bytes) {
        unsigned* codes = (unsigned*)((char*)d_ws + bpart_bytes);
        fsq_code<<<dim3(NBLK), dim3(256), 0, stream>>>(z, u, Wc, bc, cb, codes, bpart);
        fsq_expand<<<dim3(NBLK2), dim3(256), 0, stream>>>(codes, We, be, cb, zq);
        fsq_tail_bpart<<<dim3(1), dim3(256), 0, stream>>>(bpart, zq + (size_t)NROWS * CIN);
    } else {
        // fallback: R5 mono kernel (assumes ws >= 32 KB as in all prior rounds)
        fsq_mono<<<dim3(NBLK), dim3(256), 0, stream>>>(z, u, Wc, bc, We, be, cb, zq, bpart);
        fsq_tail_bpart<<<dim3(1), dim3(256), 0, stream>>>(bpart, zq + (size_t)NROWS * CIN);
    }
}